// Round 6
// baseline (125.380 us; speedup 1.0000x reference)
//
#include <hip/hip_runtime.h>
#include <math.h>

#define HW1 (1024 * 1024)
#define WID 1024
#define HEI 1024
#define NBLK 1024           // 256 main + 768 sobel
#define NMAIN 256

// Block-level reduce (wave shfl + LDS) then one atomicAdd per block.
__device__ __forceinline__ void block_atomic_add(float v, float* target, volatile float* sdata) {
#pragma unroll
    for (int off = 32; off > 0; off >>= 1)
        v += __shfl_down(v, off, 64);
    const int lane = threadIdx.x & 63;
    const int wv   = threadIdx.x >> 6;
    if (lane == 0) sdata[wv] = v;
    __syncthreads();
    if (threadIdx.x == 0) {
        float s = 0.f;
        const int nw = blockDim.x >> 6;
        for (int i = 0; i < nw; ++i) s += sdata[i];
        atomicAdd(target, s);
    }
    __syncthreads();
}

// One kernel does everything.
// Blocks [0,256):    main pass — block owns one pool row (256 pool cells);
//                    thread owns one 4x4 pixel cell; channels stay in-thread
//                    (c_loss local, no cos buffer); pd -> LDS; p_loss computed
//                    entirely in-block from LDS (row edges = conv zero-pad).
// Blocks [256,1024): Sobel s_loss on batch-0 planes (4x4 tile per thread).
// Last block to finish combines acc[] into out[0].
__global__ __launch_bounds__(256) void k_mega(const float* __restrict__ A,
                                              const float* __restrict__ B,
                                              float* __restrict__ acc,
                                              float* __restrict__ out) {
    __shared__ float pd_lds[24 * 256];   // [plane][cell] raw pooled-diff sums (x16)
    __shared__ float s1[4], s2[4], s3[4];

    const int tid = threadIdx.x;

    if (blockIdx.x < NMAIN) {
        // ---------------- main path ----------------
        const int gx = tid;            // pool-x 0..255
        const int gy = blockIdx.x;     // pool-y 0..255
        const int px = gx * 4;
        const int py = gy * 4;

        float na2[12], nb2[12], dt[12];  // [c*4 + xi]
#pragma unroll
        for (int i = 0; i < 12; ++i) { na2[i] = 0.f; nb2[i] = 0.f; dt[i] = 0.f; }
        float r_sum = 0.f;

        for (int b = 0; b < 8; ++b) {
#pragma unroll
            for (int c = 0; c < 3; ++c) {
                const size_t base = (size_t)(b * 3 + c) * HW1 + (size_t)py * WID + px;
                const float* Ap = A + base;
                const float* Bp = B + base;
                float pd = 0.f;
#pragma unroll
                for (int yy = 0; yy < 4; ++yy) {
                    const float4 a4 = *reinterpret_cast<const float4*>(Ap + yy * WID);
                    const float4 b4 = *reinterpret_cast<const float4*>(Bp + yy * WID);
                    {
                        float a = a4.x, t = b4.x;
                        na2[c * 4 + 0] += a * a; nb2[c * 4 + 0] += t * t; dt[c * 4 + 0] += a * t;
                        r_sum += fabsf(a - t); pd += t - a;
                    }
                    {
                        float a = a4.y, t = b4.y;
                        na2[c * 4 + 1] += a * a; nb2[c * 4 + 1] += t * t; dt[c * 4 + 1] += a * t;
                        r_sum += fabsf(a - t); pd += t - a;
                    }
                    {
                        float a = a4.z, t = b4.z;
                        na2[c * 4 + 2] += a * a; nb2[c * 4 + 2] += t * t; dt[c * 4 + 2] += a * t;
                        r_sum += fabsf(a - t); pd += t - a;
                    }
                    {
                        float a = a4.w, t = b4.w;
                        na2[c * 4 + 3] += a * a; nb2[c * 4 + 3] += t * t; dt[c * 4 + 3] += a * t;
                        r_sum += fabsf(a - t); pd += t - a;
                    }
                }
                pd_lds[(b * 3 + c) * 256 + gx] = pd;
            }
        }

        // c_loss for this thread's 4 pixels (channels all local)
        float c_sum = 0.f;
#pragma unroll
        for (int xi = 0; xi < 4; ++xi) {
            float cs = 0.f;
#pragma unroll
            for (int c = 0; c < 3; ++c) {
                float na = fmaxf(sqrtf(na2[c * 4 + xi]), 1e-12f);
                float nb = fmaxf(sqrtf(nb2[c * 4 + xi]), 1e-12f);
                cs += dt[c * 4 + xi] / (na * nb);
            }
            cs = fminf(fmaxf(cs, -1.0f + 1e-7f), 1.0f - 1e-7f);
            c_sum += acosf(cs);
        }

        __syncthreads();

        // p_loss fully in-block: 8 batches x 256 cells, 8 items per thread.
        // pool value = pd/16; defer the /16^2 to a single 1/256 scale.
        float p_sum = 0.f;
#pragma unroll
        for (int i = 0; i < 8; ++i) {
            const int item = i * 256 + tid;
            const int b    = item >> 8;
            const int x    = item & 255;
            const float* row = pd_lds + b * 3 * 256;
            const float g  = row[256 + x];                       // G channel
            const float gl = (x > 0)   ? row[256 + x - 1] : 0.f; // zero-pad edges
            const float gr = (x < 255) ? row[256 + x + 1] : 0.f;
            const float rr = row[x];                             // R channel
            const float bb = row[512 + x];                       // B channel
            const float d0 = g - gl;
            const float d1 = g - gr;
            const float d2 = g - rr;
            const float d3 = g - bb;
            p_sum += d0 * d0 + d1 * d1 + d2 * d2 + d3 * d3;
        }
        p_sum *= (1.0f / 256.0f);

        block_atomic_add(r_sum, acc + 0, s1);
        block_atomic_add(c_sum, acc + 1, s2);
        block_atomic_add(p_sum, acc + 3, s3);
    } else {
        // ---------------- Sobel path: 4x4 output tile per thread ----------------
        const int t   = (blockIdx.x - NMAIN) * 256 + tid;  // 0 .. 196607
        const int qx  = t & 255;
        const int rem = t >> 8;
        const int qy  = rem & 255;
        const int c   = rem >> 8;
        const int x0  = qx * 4;
        const int y0  = qy * 4;

        const float* Ap = A + (size_t)c * HW1;
        const float* Bp = B + (size_t)c * HW1;

        float rd[6][4];  // rowdiff(y,x) = d(y,x-1) - d(y,x+1), rows y0-1..y0+4
#pragma unroll
        for (int r = 0; r < 6; ++r) {
            const int yy = y0 - 1 + r;
            if (yy < 0 || yy >= HEI) {
                rd[r][0] = rd[r][1] = rd[r][2] = rd[r][3] = 0.f;
                continue;
            }
            const float* ap = Ap + (size_t)yy * WID;
            const float* bp = Bp + (size_t)yy * WID;
            const float4 a4 = *reinterpret_cast<const float4*>(ap + x0);
            const float4 b4 = *reinterpret_cast<const float4*>(bp + x0);
            const float dm = (qx > 0)   ? (ap[x0 - 1] - bp[x0 - 1]) : 0.f;
            const float dp = (qx < 255) ? (ap[x0 + 4] - bp[x0 + 4]) : 0.f;
            const float d0 = a4.x - b4.x;
            const float d1 = a4.y - b4.y;
            const float d2 = a4.z - b4.z;
            const float d3 = a4.w - b4.w;
            rd[r][0] = dm - d1;
            rd[r][1] = d0 - d2;
            rd[r][2] = d1 - d3;
            rd[r][3] = d2 - dp;
        }

        float s = 0.f;
#pragma unroll
        for (int o = 0; o < 4; ++o) {
#pragma unroll
            for (int i = 0; i < 4; ++i)
                s += fabsf(rd[o][i] + 2.f * rd[o + 1][i] + rd[o + 2][i]);
        }

        block_atomic_add(s, acc + 2, s1);
    }

    // ---------------- completion: last block combines ----------------
    __shared__ unsigned done_rank;
    __threadfence();  // make this block's atomicAdds visible device-wide
    if (tid == 0)
        done_rank = atomicAdd(reinterpret_cast<unsigned*>(acc + 8), 1u);
    __syncthreads();
    if (done_rank == NBLK - 1 && tid == 0) {
        __threadfence();  // acquire all blocks' accumulator updates
        const float r = acc[0] * (1.0f / 25165824.0f);  // mean over 8*3*1024*1024
        const float c = acc[1];
        const float s = acc[2];
        const float p = acc[3] * (1.0f / 524288.0f);    // mean over 8*256*256
        out[0] = 0.5f * c + 1.0f * r + 1.0f * p + 0.1f * s;
    }
}

extern "C" void kernel_launch(void* const* d_in, const int* in_sizes, int n_in,
                              void* d_out, int out_size, void* d_ws, size_t ws_size,
                              hipStream_t stream) {
    const float* A = (const float*)d_in[0];  // predictions
    const float* B = (const float*)d_in[1];  // targets
    float* acc = (float*)d_ws;               // acc[0..3] sums, acc[8] counter

    hipMemsetAsync(acc, 0, 64 * sizeof(float), stream);
    hipLaunchKernelGGL(k_mega, dim3(NBLK), dim3(256), 0, stream, A, B, acc, (float*)d_out);
}

// Round 8
// 114.337 us; speedup vs baseline: 1.0966x; 1.0966x over previous
//
#include <hip/hip_runtime.h>
#include <math.h>

#define HW1 (1024 * 1024)
#define WID 1024
#define HEI 1024
#define NBLK 256

typedef float f32x4 __attribute__((ext_vector_type(4)));

// Block-level reduce (wave shfl + LDS) then one atomicAdd per block.
// ALL threads of the block must call (contains __syncthreads).
__device__ __forceinline__ void block_atomic_add(float v, float* target, volatile float* sdata) {
#pragma unroll
    for (int off = 32; off > 0; off >>= 1)
        v += __shfl_down(v, off, 64);
    const int lane = threadIdx.x & 63;
    const int wv   = threadIdx.x >> 6;
    if (lane == 0) sdata[wv] = v;
    __syncthreads();
    if (threadIdx.x == 0) {
        float s = 0.f;
        const int nw = (int)(blockDim.x >> 6);
        for (int i = 0; i < nw; ++i) s += sdata[i];
        atomicAdd(target, s);
    }
    __syncthreads();
}

// One block type: block = one pool row (4 image rows x 1024 cols), all channels.
// Per batch b: reads 6 fully-contiguous 16KB runs (3 channels x {A,B}).
//  - thread (yl=tid&3, q=tid>>2) owns float4 (row 4*gy+yl, cols 4q..4q+3) of every plane
//  - na2/nb2/dt thread-local (batch loop) -> c_loss local; r_loss local
//  - pooled diff: 4-lane shfl reduce over yl -> LDS [24][256] -> p_loss in-block
//  - sobel epilogue: 768 of 1024 threads do one 4x4 tile each (L3-hot data)
//  - last block combines via completion counter.
__global__ __launch_bounds__(1024) void k_mega(const float* __restrict__ A,
                                               const float* __restrict__ B,
                                               float* __restrict__ acc,
                                               float* __restrict__ out) {
    __shared__ float pd_lds[24 * 256];   // [plane][pool-x], raw sums (x16 of pool value)
    __shared__ float sred[16];

    const int tid = threadIdx.x;
    const int gy  = blockIdx.x;          // pool row 0..255
    const int yl  = tid & 3;             // image row within pool row
    const int q   = tid >> 2;            // float4 column 0..255 == pool-x
    const int y   = gy * 4 + yl;
    const int rbase = y * 256 + q;       // float4 index within a plane

    const f32x4* A4 = reinterpret_cast<const f32x4*>(A);
    const f32x4* B4 = reinterpret_cast<const f32x4*>(B);

    float na2[3][4], nb2[3][4], dt[3][4];
#pragma unroll
    for (int c = 0; c < 3; ++c)
#pragma unroll
        for (int j = 0; j < 4; ++j) { na2[c][j] = 0.f; nb2[c][j] = 0.f; dt[c][j] = 0.f; }
    float r_sum = 0.f;

#pragma unroll 2
    for (int b = 0; b < 8; ++b) {
        f32x4 av[3], bv[3];
#pragma unroll
        for (int c = 0; c < 3; ++c) {
            const int idx = (b * 3 + c) * (HW1 / 4) + rbase;
            av[c] = __builtin_nontemporal_load(A4 + idx);
            bv[c] = __builtin_nontemporal_load(B4 + idx);
        }
#pragma unroll
        for (int c = 0; c < 3; ++c) {
            float pd = 0.f;
#pragma unroll
            for (int j = 0; j < 4; ++j) {
                const float a = av[c][j], t = bv[c][j];
                na2[c][j] += a * a; nb2[c][j] += t * t; dt[c][j] += a * t;
                r_sum += fabsf(a - t); pd += t - a;
            }
            // reduce pd over the 4 image rows (yl in low 2 lane bits)
            pd += __shfl_xor(pd, 1, 64);
            pd += __shfl_xor(pd, 2, 64);
            if (yl == 0) pd_lds[(b * 3 + c) * 256 + q] = pd;
        }
    }

    // c_loss for this thread's 4 pixels (all channels local)
    float c_sum = 0.f;
#pragma unroll
    for (int j = 0; j < 4; ++j) {
        float cs = 0.f;
#pragma unroll
        for (int c = 0; c < 3; ++c) {
            const float na = fmaxf(sqrtf(na2[c][j]), 1e-12f);
            const float nb = fmaxf(sqrtf(nb2[c][j]), 1e-12f);
            cs += dt[c][j] / (na * nb);
        }
        cs = fminf(fmaxf(cs, -1.0f + 1e-7f), 1.0f - 1e-7f);
        c_sum += acosf(cs);
    }

    __syncthreads();

    // p_loss fully in-block: 8 batches x 256 cells = 2048 items, 2 per thread.
    // pd_lds holds 16x the pool value; fold the /16^2 into one 1/256 scale.
    float p_sum = 0.f;
#pragma unroll
    for (int i = 0; i < 2; ++i) {
        const int item = i * 1024 + tid;
        const int b    = item >> 8;
        const int x    = item & 255;
        const float* row = pd_lds + b * 3 * 256;
        const float g  = row[256 + x];                       // G
        const float gl = (x > 0)   ? row[256 + x - 1] : 0.f; // conv zero-pad
        const float gr = (x < 255) ? row[256 + x + 1] : 0.f;
        const float rr = row[x];                             // R
        const float bb = row[512 + x];                       // B
        const float d0 = g - gl;
        const float d1 = g - gr;
        const float d2 = g - rr;
        const float d3 = g - bb;
        p_sum += d0 * d0 + d1 * d1 + d2 * d2 + d3 * d3;
    }
    p_sum *= (1.0f / 256.0f);

    // ---------------- sobel epilogue: 768 workers x one 4x4 tile ----------------
    float s_sum = 0.f;
    if (tid < 768) {
        const int item = gy * 768 + tid;   // 0 .. 196607
        const int qx   = item & 255;
        const int rem  = item >> 8;
        const int qy   = rem & 255;
        const int c    = rem >> 8;
        const int x0   = qx * 4;
        const int y0   = qy * 4;

        const float* Ap = A + (size_t)c * HW1;
        const float* Bp = B + (size_t)c * HW1;

        float rd[6][4];  // rowdiff(y,x) = d(y,x-1) - d(y,x+1), rows y0-1..y0+4
#pragma unroll
        for (int r = 0; r < 6; ++r) {
            const int yy = y0 - 1 + r;
            if (yy < 0 || yy >= HEI) {
                rd[r][0] = rd[r][1] = rd[r][2] = rd[r][3] = 0.f;
                continue;
            }
            const float* ap = Ap + (size_t)yy * WID;
            const float* bp = Bp + (size_t)yy * WID;
            const float4 a4 = *reinterpret_cast<const float4*>(ap + x0);
            const float4 b4 = *reinterpret_cast<const float4*>(bp + x0);
            const float dm = (qx > 0)   ? (ap[x0 - 1] - bp[x0 - 1]) : 0.f;
            const float dp = (qx < 255) ? (ap[x0 + 4] - bp[x0 + 4]) : 0.f;
            const float d0 = a4.x - b4.x;
            const float d1 = a4.y - b4.y;
            const float d2 = a4.z - b4.z;
            const float d3 = a4.w - b4.w;
            rd[r][0] = dm - d1;
            rd[r][1] = d0 - d2;
            rd[r][2] = d1 - d3;
            rd[r][3] = d2 - dp;
        }
#pragma unroll
        for (int o = 0; o < 4; ++o)
#pragma unroll
            for (int i = 0; i < 4; ++i)
                s_sum += fabsf(rd[o][i] + 2.f * rd[o + 1][i] + rd[o + 2][i]);
    }

    block_atomic_add(r_sum, acc + 0, sred);
    block_atomic_add(c_sum, acc + 1, sred);
    block_atomic_add(s_sum, acc + 2, sred);
    block_atomic_add(p_sum, acc + 3, sred);

    // ---------------- completion: last block combines ----------------
    __shared__ unsigned done_rank;
    __threadfence();  // make this block's atomicAdds visible device-wide
    if (tid == 0)
        done_rank = atomicAdd(reinterpret_cast<unsigned*>(acc + 8), 1u);
    __syncthreads();
    if (done_rank == NBLK - 1 && tid == 0) {
        __threadfence();  // acquire all blocks' accumulator updates
        const float r = acc[0] * (1.0f / 25165824.0f);  // mean over 8*3*1024*1024
        const float c = acc[1];
        const float s = acc[2];
        const float p = acc[3] * (1.0f / 524288.0f);    // mean over 8*256*256
        out[0] = 0.5f * c + 1.0f * r + 1.0f * p + 0.1f * s;
    }
}

extern "C" void kernel_launch(void* const* d_in, const int* in_sizes, int n_in,
                              void* d_out, int out_size, void* d_ws, size_t ws_size,
                              hipStream_t stream) {
    const float* A = (const float*)d_in[0];  // predictions
    const float* B = (const float*)d_in[1];  // targets
    float* acc = (float*)d_ws;               // acc[0..3] sums, acc[8] counter

    hipMemsetAsync(acc, 0, 64 * sizeof(float), stream);
    hipLaunchKernelGGL(k_mega, dim3(NBLK), dim3(1024), 0, stream, A, B, acc, (float*)d_out);
}